// Round 14
// baseline (198.967 us; speedup 1.0000x reference)
//
#include <hip/hip_runtime.h>

#define CHUNK 4096      // edges per partition block (512 threads x 8)
#define ITERS 8

typedef __attribute__((ext_vector_type(8))) short short8;   // 8 bf16 (4 VGPR)
typedef __attribute__((ext_vector_type(4))) float f32x4;    // mfma acc

// fp32 -> bf16 (RNE) pack of two values into one uint (lo = a, hi = b).
__device__ inline unsigned packbf2(float a, float b) {
    unsigned ua = __float_as_uint(a), ub = __float_as_uint(b);
    ua = (ua + 0x7fffu + ((ua >> 16) & 1u)) >> 16;
    ub = (ub + 0x7fffu + ((ub >> 16) & 1u)) >> 16;
    return ua | (ub << 16);
}
// fp32 -> bf16 bits (RNE)
__device__ inline unsigned short bf16r(float f) {
    unsigned u = __float_as_uint(f);
    return (unsigned short)((u + 0x7fffu + ((u >> 16) & 1u)) >> 16);
}
// bf16 pair (one uint) -> two floats.
__device__ inline float bflo(unsigned w) { return __uint_as_float(w << 16); }
__device__ inline float bfhi(unsigned w) { return __uint_as_float(w & 0xffff0000u); }

// ---------------------------------------------------------------------------
// Convert x (N x 16 fp32) -> xb (N x 16 bf16). 8 elements per thread.
__global__ __launch_bounds__(256) void k_xcvt(
    const float* __restrict__ x, unsigned short* __restrict__ xb, int n8)
{
    int i = blockIdx.x * 256 + threadIdx.x;
    if (i >= n8) return;
    const float4* xp = reinterpret_cast<const float4*>(x) + (size_t)i * 2;
    float4 a = xp[0], b = xp[1];
    uint4 w;
    w.x = packbf2(a.x, a.y); w.y = packbf2(a.z, a.w);
    w.z = packbf2(b.x, b.y); w.w = packbf2(b.z, b.w);
    reinterpret_cast<uint4*>(xb)[i] = w;
}

// ---------------------------------------------------------------------------
// Bucket histogram: bucket = dst >> 8 (256 nodes per bucket), NB <= 512.
__global__ __launch_bounds__(512) void k_bhist(
    const int* __restrict__ ei, int* __restrict__ bhist, int E, int NB)
{
    __shared__ int cnt[512];
    int t = threadIdx.x;
    cnt[t] = 0;
    __syncthreads();
    int base = blockIdx.x * CHUNK;
#pragma unroll
    for (int i = 0; i < ITERS; ++i) {
        int e = base + i * 512 + t;
        if (e < E) {
            int dst = ei[E + e];
            atomicAdd(&cnt[dst >> 8], 1);
        }
    }
    __syncthreads();
    if (t < NB && cnt[t]) atomicAdd(&bhist[t], cnt[t]);
}

// Exclusive scan of bucket counts (NB <= 512), writes bstart + cursor init.
__global__ __launch_bounds__(512) void k_bscan(
    const int* __restrict__ bhist, int* __restrict__ bstart,
    int* __restrict__ gcursor, int NB, int E)
{
    __shared__ int s[512];
    int t = threadIdx.x;
    int v0 = (t < NB) ? bhist[t] : 0;
    s[t] = v0;
    __syncthreads();
    for (int off = 1; off < 512; off <<= 1) {
        int v = (t >= off) ? s[t - off] : 0;
        __syncthreads();
        s[t] += v;
        __syncthreads();
    }
    if (t < NB) { int ex = s[t] - v0; bstart[t] = ex; gcursor[t] = ex; }
    if (t == 0) bstart[NB] = E;
}

// Partition edges into bucket-contiguous packed list, coalesced flush.
// packed = (src << 8) | (dst & 255); requires N < 2^17 (holds: 100000).
__global__ __launch_bounds__(512) void k_partition(
    const int* __restrict__ ei, int* __restrict__ gcursor,
    int* __restrict__ epack, int E)
{
    __shared__ int cnt[512], sc[512], lbase[512], gbase[512], lcnt[512];
    __shared__ int stage[CHUNK];
    __shared__ unsigned short stageb[CHUNK];
    int t = threadIdx.x;
    cnt[t] = 0; lcnt[t] = 0;
    __syncthreads();

    int base = blockIdx.x * CHUNK;
    int pk[ITERS], bb[ITERS];
#pragma unroll
    for (int i = 0; i < ITERS; ++i) {
        int e = base + i * 512 + t;
        if (e < E) {
            int src = ei[e], dst = ei[E + e];
            pk[i] = (src << 8) | (dst & 255);
            bb[i] = dst >> 8;
            atomicAdd(&cnt[bb[i]], 1);
        } else bb[i] = -1;
    }
    __syncthreads();

    int v0 = cnt[t];
    sc[t] = v0;
    __syncthreads();
    for (int off = 1; off < 512; off <<= 1) {
        int v = (t >= off) ? sc[t - off] : 0;
        __syncthreads();
        sc[t] += v;
        __syncthreads();
    }
    lbase[t] = sc[t] - v0;
    if (v0 > 0) gbase[t] = atomicAdd(&gcursor[t], v0);
    __syncthreads();

#pragma unroll
    for (int i = 0; i < ITERS; ++i) {
        if (bb[i] >= 0) {
            int loc = atomicAdd(&lcnt[bb[i]], 1);
            int slot = lbase[bb[i]] + loc;
            stage[slot] = pk[i];
            stageb[slot] = (unsigned short)bb[i];
        }
    }
    __syncthreads();

    int m = min(CHUNK, E - base);
#pragma unroll
    for (int i = 0; i < ITERS; ++i) {
        int slot = i * 512 + t;
        if (slot < m) {
            int b = stageb[slot];
            epack[gbase[b] + (slot - lbase[b])] = stage[slot];
        }
    }
}

// ---------------------------------------------------------------------------
// Per-bucket counting sort by dst&255 -> per-node CSR (rs + esorted of src).
__global__ __launch_bounds__(256) void k_sort(
    const int* __restrict__ bstart, const int* __restrict__ epack,
    int* __restrict__ rs, int* __restrict__ esorted, int N, int E)
{
    __shared__ int hist[256], cur[256], sc[256];
    int t = threadIdx.x;
    int b = blockIdx.x;
    int s0 = bstart[b], s1 = bstart[b + 1];
    hist[t] = 0;
    __syncthreads();
    for (int e = s0 + t; e < s1; e += 256)
        atomicAdd(&hist[epack[e] & 255], 1);
    __syncthreads();

    int v0 = hist[t];
    sc[t] = v0;
    __syncthreads();
    for (int off = 1; off < 256; off <<= 1) {
        int v = (t >= off) ? sc[t - off] : 0;
        __syncthreads();
        sc[t] += v;
        __syncthreads();
    }
    int excl = sc[t] - v0;
    cur[t] = excl;
    int node = (b << 8) + t;
    if (node < N) rs[node] = s0 + excl;
    if (b == 0 && t == 0) rs[N] = E;
    __syncthreads();

    for (int e = s0 + t; e < s1; e += 256) {
        int pk = epack[e];
        int dlo = pk & 255;
        int pos = s0 + atomicAdd(&cur[dlo], 1);
        esorted[pos] = ((unsigned)pk) >> 8;
    }
}

// ---------------------------------------------------------------------------
// MFMA fused gather(F=16) + layer1. One wave = 16 nodes.
// layer1 = [x | agg] (16x32) @ [Wroot ; Wrel] (32x32) + b  -> 2 mfma.
// Fragment mapping (verified in round-13 k_g2f):
//   A[m][k]: m = lane&15, k = (lane>>4)*8 + i
//   B[k][j]: j = lane&15, k = (lane>>4)*8 + i
//   D[m][j]: j = lane&15, m = (lane>>4)*4 + r
__global__ __launch_bounds__(256) void k_g1f(
    const unsigned short* __restrict__ xb,
    const int* __restrict__ rs, const int* __restrict__ esrc,
    const float* __restrict__ wroot, const float* __restrict__ wrel,
    const float* __restrict__ bias, unsigned short* __restrict__ h1, int N)
{
    __shared__ __attribute__((aligned(16))) unsigned short aggl[4][16][24]; // 16+8 pad
    __shared__ __attribute__((aligned(16))) unsigned short h1l[4][16][40];  // 32+8 pad

    int t = threadIdx.x;
    int w = t >> 6, l = t & 63;
    int m = l & 15, q4 = l >> 4;
    int nb = (blockIdx.x * 4 + w) * 16;
    if (nb >= N) return;
    int n = nb + m;

    // B fragment: stacked [Wroot; Wrel] (32x32) as bf16, 2 j-tiles.
    short8 fb[2];
#pragma unroll
    for (int nt = 0; nt < 2; ++nt) {
#pragma unroll
        for (int i = 0; i < 8; ++i) {
            int k = q4 * 8 + i, j = nt * 16 + m;
            float wv = (k < 16) ? wroot[k * 32 + j] : wrel[(k - 16) * 32 + j];
            fb[nt][i] = (short)bf16r(wv);
        }
    }

    // Gather: 4 lanes per node (q4 = feature quarter), 4 features each.
    int s0 = 0, s1 = 0;
    if (n < N) { s0 = rs[n]; s1 = rs[n + 1]; }
    float g0 = 0, g1 = 0, g2 = 0, g3 = 0;
    int e = s0;
    for (; e + 7 < s1; e += 8) {                   // 8 loads in flight
        uint2 v[8];
#pragma unroll
        for (int u = 0; u < 8; ++u) {
            int src = esrc[e + u];
            v[u] = *reinterpret_cast<const uint2*>(xb + (size_t)src * 16 + q4 * 4);
        }
#pragma unroll
        for (int u = 0; u < 8; ++u) {
            g0 += bflo(v[u].x); g1 += bfhi(v[u].x);
            g2 += bflo(v[u].y); g3 += bfhi(v[u].y);
        }
    }
    for (; e < s1; ++e) {
        int src = esrc[e];
        uint2 v0 = *reinterpret_cast<const uint2*>(xb + (size_t)src * 16 + q4 * 4);
        g0 += bflo(v0.x); g1 += bfhi(v0.x);
        g2 += bflo(v0.y); g3 += bfhi(v0.y);
    }
    // bounce agg to LDS for A-fragment redistribution
    uint2 pg;
    pg.x = packbf2(g0, g1);
    pg.y = packbf2(g2, g3);
    *reinterpret_cast<uint2*>(&aggl[w][m][q4 * 4]) = pg;

    // A fragment: k<16 from xb row (q4 0..1), k>=16 from aggl (q4 2..3).
    short8 af;
    {
        uint4 v = make_uint4(0, 0, 0, 0);
        if (q4 < 2) {
            if (n < N)
                v = *reinterpret_cast<const uint4*>(xb + (size_t)n * 16 + q4 * 8);
        } else {
            v = *reinterpret_cast<const uint4*>(&aggl[w][m][(q4 - 2) * 8]);
        }
        __builtin_memcpy(&af, &v, 16);
    }

    // layer1: 2 mfma (bias preloaded).
    f32x4 acc[2];
#pragma unroll
    for (int nt = 0; nt < 2; ++nt) {
        float bj = bias[nt * 16 + m];
        acc[nt] = (f32x4){bj, bj, bj, bj};
        acc[nt] = __builtin_amdgcn_mfma_f32_16x16x32_bf16(af, fb[nt], acc[nt], 0, 0, 0);
    }

    // relu + bf16 pack via LDS bounce (D layout -> row layout), uint4 store.
#pragma unroll
    for (int nt = 0; nt < 2; ++nt)
#pragma unroll
        for (int r = 0; r < 4; ++r)
            h1l[w][q4 * 4 + r][nt * 16 + m] = bf16r(fmaxf(acc[nt][r], 0.f));

    uint4 hv = *reinterpret_cast<const uint4*>(&h1l[w][m][q4 * 8]);
    if (n < N)
        reinterpret_cast<uint4*>(h1 + (size_t)n * 32)[q4] = hv;
}

// ---------------------------------------------------------------------------
// MFMA-based fused gather + layer2 + fc1 + fc2 (round-13 form, verified).
__global__ __launch_bounds__(256) void k_g2f(
    const unsigned short* __restrict__ h1, const int* __restrict__ rs,
    const int* __restrict__ esrc,
    const float* __restrict__ wroot, const float* __restrict__ wrel,
    const float* __restrict__ bias,
    const float* __restrict__ f1w, const float* __restrict__ f1b,
    const float* __restrict__ f2w, const float* __restrict__ f2b,
    float* __restrict__ out, int N)
{
    __shared__ __attribute__((aligned(16))) unsigned short h2l[4][16][72]; // 64+8 pad
    __shared__ __attribute__((aligned(16))) unsigned short fl[4][16][40];  // 32+8 pad

    int t = threadIdx.x;
    int w = t >> 6, l = t & 63;
    int m = l & 15, q4 = l >> 4;
    int tile = blockIdx.x * 4 + w;
    int nb = tile * 16;
    if (nb >= N) return;

    // ---- weight fragments (VGPR-resident bf16) ----
    short8 fwr[4], fwl[4];
#pragma unroll
    for (int nt = 0; nt < 4; ++nt) {
#pragma unroll
        for (int i = 0; i < 8; ++i) {
            int k = q4 * 8 + i, j = nt * 16 + m;
            fwr[nt][i] = (short)bf16r(wroot[k * 64 + j]);
            fwl[nt][i] = (short)bf16r(wrel[k * 64 + j]);
        }
    }
    short8 ff1[2][2];
#pragma unroll
    for (int ks = 0; ks < 2; ++ks)
#pragma unroll
        for (int nt = 0; nt < 2; ++nt)
#pragma unroll
            for (int i = 0; i < 8; ++i)
                ff1[ks][nt][i] = (short)bf16r(f1w[(ks * 32 + q4 * 8 + i) * 32 + nt * 16 + m]);
    short8 ff2;
#pragma unroll
    for (int i = 0; i < 8; ++i)
        ff2[i] = (short)bf16r(f2w[(q4 * 8 + i) * 16 + m]);

    // ---- gather: node nb+m, features q4*8..+8 of agg2 from bf16 h1 rows ----
    int n = nb + m;
    int s0 = 0, s1 = 0;
    if (n < N) { s0 = rs[n]; s1 = rs[n + 1]; }
    float ga0 = 0, ga1 = 0, ga2 = 0, ga3 = 0, ga4 = 0, ga5 = 0, ga6 = 0, ga7 = 0;
#define ACC8(W) { ga0 += bflo((W).x); ga1 += bfhi((W).x); \
                  ga2 += bflo((W).y); ga3 += bfhi((W).y); \
                  ga4 += bflo((W).z); ga5 += bfhi((W).z); \
                  ga6 += bflo((W).w); ga7 += bfhi((W).w); }
    int e = s0;
    for (; e + 3 < s1; e += 4) {                     // 4 row-loads in flight
        int sa = esrc[e], sb = esrc[e + 1], sc2 = esrc[e + 2], sd = esrc[e + 3];
        uint4 wa = *reinterpret_cast<const uint4*>(h1 + (size_t)sa * 32 + q4 * 8);
        uint4 wb = *reinterpret_cast<const uint4*>(h1 + (size_t)sb * 32 + q4 * 8);
        uint4 wc = *reinterpret_cast<const uint4*>(h1 + (size_t)sc2 * 32 + q4 * 8);
        uint4 wd = *reinterpret_cast<const uint4*>(h1 + (size_t)sd * 32 + q4 * 8);
        ACC8(wa) ACC8(wb) ACC8(wc) ACC8(wd)
    }
    for (; e < s1; ++e) {
        int sa = esrc[e];
        uint4 wa = *reinterpret_cast<const uint4*>(h1 + (size_t)sa * 32 + q4 * 8);
        ACC8(wa)
    }
#undef ACC8

    // a-frag: self row (already bf16); g-frag: pack gathered sums.
    short8 af;
    {
        uint4 av = make_uint4(0, 0, 0, 0);
        if (n < N) av = *reinterpret_cast<const uint4*>(h1 + (size_t)n * 32 + q4 * 8);
        __builtin_memcpy(&af, &av, 16);
    }
    short8 gf;
    gf[0] = (short)bf16r(ga0); gf[1] = (short)bf16r(ga1);
    gf[2] = (short)bf16r(ga2); gf[3] = (short)bf16r(ga3);
    gf[4] = (short)bf16r(ga4); gf[5] = (short)bf16r(ga5);
    gf[6] = (short)bf16r(ga6); gf[7] = (short)bf16r(ga7);

    // ---- layer2: h2 = a@Wroot + g@Wrel + b  (8 mfma) ----
    f32x4 acc[4];
#pragma unroll
    for (int nt = 0; nt < 4; ++nt) {
        float bj = bias[nt * 16 + m];
        acc[nt] = (f32x4){bj, bj, bj, bj};
        acc[nt] = __builtin_amdgcn_mfma_f32_16x16x32_bf16(af, fwr[nt], acc[nt], 0, 0, 0);
        acc[nt] = __builtin_amdgcn_mfma_f32_16x16x32_bf16(gf, fwl[nt], acc[nt], 0, 0, 0);
    }
    // relu + bounce to LDS (D layout -> A layout)
#pragma unroll
    for (int nt = 0; nt < 4; ++nt)
#pragma unroll
        for (int r = 0; r < 4; ++r)
            h2l[w][q4 * 4 + r][nt * 16 + m] = bf16r(fmaxf(acc[nt][r], 0.f));

    short8 h2a[2];
#pragma unroll
    for (int ks = 0; ks < 2; ++ks) {
        uint4 v = *reinterpret_cast<const uint4*>(&h2l[w][m][ks * 32 + q4 * 8]);
        __builtin_memcpy(&h2a[ks], &v, 16);
    }

    // ---- fc1 (4 mfma) ----
    f32x4 fa[2];
#pragma unroll
    for (int nt = 0; nt < 2; ++nt) {
        float bj = f1b[nt * 16 + m];
        fa[nt] = (f32x4){bj, bj, bj, bj};
        fa[nt] = __builtin_amdgcn_mfma_f32_16x16x32_bf16(h2a[0], ff1[0][nt], fa[nt], 0, 0, 0);
        fa[nt] = __builtin_amdgcn_mfma_f32_16x16x32_bf16(h2a[1], ff1[1][nt], fa[nt], 0, 0, 0);
    }
#pragma unroll
    for (int nt = 0; nt < 2; ++nt)
#pragma unroll
        for (int r = 0; r < 4; ++r)
            fl[w][q4 * 4 + r][nt * 16 + m] = bf16r(fmaxf(fa[nt][r], 0.f));

    short8 ffr;
    {
        uint4 v = *reinterpret_cast<const uint4*>(&fl[w][m][q4 * 8]);
        __builtin_memcpy(&ffr, &v, 16);
    }

    // ---- fc2 (1 mfma) + store ----
    float bj2 = f2b[m];
    f32x4 oacc = (f32x4){bj2, bj2, bj2, bj2};
    oacc = __builtin_amdgcn_mfma_f32_16x16x32_bf16(ffr, ff2, oacc, 0, 0, 0);
#pragma unroll
    for (int r = 0; r < 4; ++r) {
        int node = nb + q4 * 4 + r;
        if (node < N) out[(size_t)node * 16 + m] = oacc[r];
    }
}

// ---------------------------------------------------------------------------
extern "C" void kernel_launch(void* const* d_in, const int* in_sizes, int n_in,
                              void* d_out, int out_size, void* d_ws, size_t ws_size,
                              hipStream_t stream)
{
    const float* x   = (const float*)d_in[0];
    const int*   ei  = (const int*)d_in[1];
    const float* wr1 = (const float*)d_in[2];
    const float* wl1 = (const float*)d_in[3];
    const float* b1  = (const float*)d_in[4];
    const float* wr2 = (const float*)d_in[5];
    const float* wl2 = (const float*)d_in[6];
    const float* b2  = (const float*)d_in[7];
    const float* f1w = (const float*)d_in[8];
    const float* f1b = (const float*)d_in[9];
    const float* f2w = (const float*)d_in[10];
    const float* f2b = (const float*)d_in[11];
    float* out = (float*)d_out;

    const int N  = in_sizes[0] / 16;
    const int E  = in_sizes[1] / 2;
    const int NB = (N + 255) >> 8;      // 256 nodes per bucket, NB <= 512

    // Workspace layout (no aliasing; ~23MB of >=51.2MB):
    //   h1      : N*32 bf16 (= N*16 float slots)   6.4 MB
    //   xb      : N*16 bf16 (= N*8  float slots)   3.2 MB
    //   esorted : E ints
    //   epack   : E ints
    //   rs      : N+1 ints; bhist/bstart/gcursor tiny
    float*          ws      = (float*)d_ws;
    unsigned short* h1      = (unsigned short*)ws;
    unsigned short* xb      = (unsigned short*)(ws + (size_t)N * 16);
    int*            esorted = (int*)(ws + (size_t)N * 24);
    int*            epack   = esorted + E;
    int*            rs      = epack + E;
    int*            bhist   = rs + N + 1;
    int*            bstart  = bhist + NB;
    int*            gcursor = bstart + NB + 1;

    hipMemsetAsync(bhist, 0, (size_t)NB * sizeof(int), stream);

    int nchunk = (E + CHUNK - 1) / CHUNK;
    int g_cv = (N * 2 + 255) / 256;
    int g_mf = (N + 63) / 64;           // 4 waves/block, 16 nodes/wave

    k_xcvt     <<<g_cv,   256, 0, stream>>>(x, xb, N * 2);
    k_bhist    <<<nchunk, 512, 0, stream>>>(ei, bhist, E, NB);
    k_bscan    <<<1,      512, 0, stream>>>(bhist, bstart, gcursor, NB, E);
    k_partition<<<nchunk, 512, 0, stream>>>(ei, gcursor, epack, E);
    k_sort     <<<NB,     256, 0, stream>>>(bstart, epack, rs, esorted, N, E);

    k_g1f      <<<g_mf, 256, 0, stream>>>(xb, rs, esorted, wr1, wl1, b1, h1, N);
    k_g2f      <<<g_mf, 256, 0, stream>>>(h1, rs, esorted, wr2, wl2, b2,
                                          f1w, f1b, f2w, f2b, out, N);
}